// Round 1
// baseline (734.747 us; speedup 1.0000x reference)
//
#include <hip/hip_runtime.h>
#include <math.h>

// Problem constants (fixed by the reference)
#define BATCH 16
#define SMAX 4096
#define DMODEL 4096
#define NH 32
#define NKV 8
#define NREP 4
#define DH 128
#define QKCOLS 5120   // 4096 (q) + 1024 (k)
#define NCHUNK 8      // s-dimension split for flash-decode
#define CHUNK 512     // positions per chunk
#define TILE 64       // positions per LDS tile

// ---------------------------------------------------------------------------
// GEMV partials: part[ch][b][col] = sum_{d in chunk} in[b][d] * w[d][col]
// cols [0,c1) from w1 (row stride c1), cols [c1,c1+c2) from w2 (row stride c2)
// grid: (totC/256 col-tiles, 16 d-chunks), block 256
// ---------------------------------------------------------------------------
__global__ __launch_bounds__(256) void gemv_part(
    const float* __restrict__ in,   // [16][4096]
    const float* __restrict__ w1, int c1,
    const float* __restrict__ w2, int c2,
    float* __restrict__ part)       // [16][16][c1+c2]
{
    const int tile = blockIdx.x;
    const int ch = blockIdx.y;
    const int t = threadIdx.x;
    const int col = tile * 256 + t;
    const int totC = c1 + c2;
    const int d0 = ch * 256;

    __shared__ float xs[BATCH * 256];
    for (int b = 0; b < BATCH; ++b)
        xs[b * 256 + t] = in[(size_t)b * DMODEL + d0 + t];
    __syncthreads();

    const float* w; int stride, wcol;
    if (col < c1) { w = w1; stride = c1; wcol = col; }
    else          { w = w2; stride = c2; wcol = col - c1; }

    float acc[BATCH];
#pragma unroll
    for (int b = 0; b < BATCH; ++b) acc[b] = 0.f;

    const float* wp = w + (size_t)d0 * stride + wcol;
    for (int d = 0; d < 256; d += 4) {
        float wa = wp[(size_t)(d + 0) * stride];
        float wb = wp[(size_t)(d + 1) * stride];
        float wc = wp[(size_t)(d + 2) * stride];
        float wd = wp[(size_t)(d + 3) * stride];
#pragma unroll
        for (int b = 0; b < BATCH; ++b) {
            const float4 xv = *(const float4*)&xs[b * 256 + d];
            float a = acc[b];
            a = fmaf(xv.x, wa, a);
            a = fmaf(xv.y, wb, a);
            a = fmaf(xv.z, wc, a);
            a = fmaf(xv.w, wd, a);
            acc[b] = a;
        }
    }
#pragma unroll
    for (int b = 0; b < BATCH; ++b)
        part[((size_t)ch * BATCH + b) * totC + col] = acc[b];
}

// ---------------------------------------------------------------------------
// Reduce 16 partials + apply RoPE (interleaved even/odd pairs). 40960 pairs.
// ---------------------------------------------------------------------------
__global__ __launch_bounds__(256) void rope_reduce(
    const float* __restrict__ part,  // [16][16][5120]
    const float* __restrict__ fcos, const float* __restrict__ fsin,
    float* __restrict__ xqk)         // [16][5120]
{
    int g = blockIdx.x * 256 + threadIdx.x;      // pair id: 16*2560
    int b = g / 2560;
    int po = g % 2560;
    float e = 0.f, o = 0.f;
    const float* p = part + (size_t)b * QKCOLS + 2 * po;
#pragma unroll
    for (int ch = 0; ch < 16; ++ch) {
        float2 v = *(const float2*)(p + (size_t)ch * BATCH * QKCOLS);
        e += v.x; o += v.y;
    }
    int i = po & 63;                 // pair index within a head (DH/2 = 64)
    float c = fcos[i], s = fsin[i];
    xqk[(size_t)b * QKCOLS + 2 * po]     = e * c - o * s;
    xqk[(size_t)b * QKCOLS + 2 * po + 1] = e * s + o * c;
}

// ---------------------------------------------------------------------------
// Flash-decode attention partial (V == K!). grid (8 chunks, 8 kv, 16 b),
// block 256 = 4 waves, wave r owns rep r. Writes (acc[128], m, l) per record.
// ---------------------------------------------------------------------------
__global__ __launch_bounds__(256) void attn_part_kernel(
    const float* __restrict__ cache_k,  // [16][4096][8][128]
    const float* __restrict__ xqk,      // [16][5120]
    const int* __restrict__ sp,
    float* __restrict__ out)            // [b][kv][chunk][r][130]
{
    const int chunk = blockIdx.x;
    const int kv = blockIdx.y;
    const int b = blockIdx.z;
    const int t = threadIdx.x;
    const int dl = t & 63;
    const int r = t >> 6;
    const int start_pos = sp[0];

    __shared__ float k_lds[TILE * DH];  // 32 KB, unpadded (sequential accesses)

    const int h = kv * NREP + r;
    const float* qp = xqk + (size_t)b * QKCOLS + h * DH;
    const int half = dl & 31;           // lane within half-wave
    const int hi = dl >> 5;             // which half-wave
    // q fragment for score phase: 4 floats at col half*4 (fixed per lane)
    float4 q4 = *(const float4*)(qp + half * 4);
    const float scale = 0.08838834764831845f;  // 1/sqrt(128)
    q4.x *= scale; q4.y *= scale; q4.z *= scale; q4.w *= scale;
    // q fragment for nothing else; PV uses float2 ownership at col 2*dl
    const int row_owned = (half << 1) + hi;    // permuted row ownership

    const float* xknew = xqk + (size_t)b * QKCOLS + DMODEL + kv * DH;
    const float* kbase = cache_k + ((size_t)b * SMAX * NKV + kv) * DH;

    float m_run = -1e30f, l_run = 0.f;
    float2 acc = make_float2(0.f, 0.f);

    for (int tt = 0; tt < CHUNK / TILE; ++tt) {
        const int s_base = chunk * CHUNK + tt * TILE;
        // coalesced load: 64 rows x 512B; 8 float4 per thread
#pragma unroll
        for (int it = 0; it < 8; ++it) {
            int f = it * 256 + t;
            int row = f >> 5;
            int c4 = (f & 31) * 4;
            int s = s_base + row;
            const float* src = (s == start_pos) ? (xknew + c4)
                             : (kbase + (size_t)s * (NKV * DH) + c4);
            *(float4*)&k_lds[row * DH + c4] = *(const float4*)src;
        }
        __syncthreads();

        // ---- scores: half-wave butterfly, 2 rows per iteration ----
        float score_mine = -1e30f;
        for (int jp = 0; jp < 32; ++jp) {
            int row = 2 * jp + hi;
            const float4 k4 = *(const float4*)&k_lds[row * DH + half * 4];
            float partial = q4.x * k4.x + q4.y * k4.y + q4.z * k4.z + q4.w * k4.w;
#pragma unroll
            for (int m = 1; m < 32; m <<= 1)
                partial += __shfl_xor(partial, m, 64);   // stays within half-wave
            if (half == jp) score_mine = partial;        // lane dl owns row_owned
        }
        if (s_base + row_owned > start_pos) score_mine = -1e30f;

        // ---- online softmax (wave-private: one rep per wave) ----
        float m_tile = score_mine;
#pragma unroll
        for (int m = 1; m < 64; m <<= 1)
            m_tile = fmaxf(m_tile, __shfl_xor(m_tile, m, 64));
        float m_new = fmaxf(m_run, m_tile);
        float alpha = __expf(m_run - m_new);
        float p_mine = __expf(score_mine - m_new);
        float psum = p_mine;
#pragma unroll
        for (int m = 1; m < 64; m <<= 1)
            psum += __shfl_xor(psum, m, 64);
        l_run = l_run * alpha + psum;
        acc.x *= alpha; acc.y *= alpha;
        m_run = m_new;

        // ---- PV accumulate (V == K), conflict-free sequential b64 reads ----
        for (int j = 0; j < 64; ++j) {
            int src_lane = (j >> 1) + ((j & 1) << 5);    // lane owning row j
            float pj = __shfl(p_mine, src_lane, 64);
            const float2 kj = *(const float2*)&k_lds[j * DH + 2 * dl];
            acc.x = fmaf(pj, kj.x, acc.x);
            acc.y = fmaf(pj, kj.y, acc.y);
        }
        __syncthreads();
    }

    float* rec = out + ((((size_t)b * NKV + kv) * NCHUNK + chunk) * NREP + r) * 130;
    rec[2 * dl] = acc.x;
    rec[2 * dl + 1] = acc.y;
    if (dl == 0) { rec[128] = m_run; rec[129] = l_run; }
}

// ---------------------------------------------------------------------------
// Combine chunk partials -> attn_out[b][h*128+d]. grid (32 h, 16 b), 128 thr.
// ---------------------------------------------------------------------------
__global__ __launch_bounds__(128) void attn_combine(
    const float* __restrict__ part, float* __restrict__ attn_out)
{
    const int hq = blockIdx.x;
    const int b = blockIdx.y;
    const int kv = hq >> 2, r = hq & 3;
    const int d = threadIdx.x;
    float m_c[NCHUNK], l_c[NCHUNK];
    float M = -1e30f;
#pragma unroll
    for (int c = 0; c < NCHUNK; ++c) {
        const float* rec = part + ((((size_t)b * NKV + kv) * NCHUNK + c) * NREP + r) * 130;
        m_c[c] = rec[128]; l_c[c] = rec[129];
        M = fmaxf(M, m_c[c]);
    }
    float num = 0.f, den = 0.f;
#pragma unroll
    for (int c = 0; c < NCHUNK; ++c) {
        const float* rec = part + ((((size_t)b * NKV + kv) * NCHUNK + c) * NREP + r) * 130;
        float w = __expf(m_c[c] - M);
        num = fmaf(w, rec[d], num);
        den = fmaf(w, l_c[c], den);
    }
    attn_out[(size_t)b * DMODEL + hq * DH + d] = num / den;
}

// ---------------------------------------------------------------------------
// Final reduce of output-projection partials -> d_out (fp32)
// ---------------------------------------------------------------------------
__global__ __launch_bounds__(256) void reduce_out(
    const float* __restrict__ part, float* __restrict__ out)
{
    int g = blockIdx.x * 256 + threadIdx.x;   // 0..65535
    int b = g >> 12, o = g & 4095;
    float s = 0.f;
#pragma unroll
    for (int ch = 0; ch < 16; ++ch)
        s += part[((size_t)ch * BATCH + b) * DMODEL + o];
    out[g] = s;
}

extern "C" void kernel_launch(void* const* d_in, const int* in_sizes, int n_in,
                              void* d_out, int out_size, void* d_ws, size_t ws_size,
                              hipStream_t stream) {
    const float* x       = (const float*)d_in[0];
    const float* cache_k = (const float*)d_in[1];
    // d_in[2] = cache_v: UNUSED (reference's PV einsum uses keys)
    const float* wq      = (const float*)d_in[3];
    const float* wk      = (const float*)d_in[4];
    // d_in[5] = wv: UNUSED
    const float* wo      = (const float*)d_in[6];
    const float* fcos    = (const float*)d_in[7];
    const float* fsin    = (const float*)d_in[8];
    const int*   sp      = (const int*)d_in[9];
    float* out = (float*)d_out;
    float* ws  = (float*)d_ws;

    // ws layout (floats); part_qk region reused for part_out (disjoint lifetime)
    float* part_qk   = ws;                        // 16*16*5120 = 1,310,720
    float* xqk       = part_qk + 1310720;         // 16*5120    =    81,920
    float* attn_part = xqk + 81920;               // 16*8*8*4*130 = 532,480
    float* attn_out  = attn_part + 532480;        // 16*4096    =    65,536
    float* part_out  = part_qk;                   // 16*16*4096 = 1,048,576 (reuse)

    // 1) x @ [wq | wk] partials
    gemv_part<<<dim3(QKCOLS / 256, 16), 256, 0, stream>>>(x, wq, 4096, wk, 1024, part_qk);
    // 2) reduce + RoPE
    rope_reduce<<<160, 256, 0, stream>>>(part_qk, fcos, fsin, xqk);
    // 3) flash-decode attention partials (single pass over cache_k, V==K)
    attn_part_kernel<<<dim3(NCHUNK, NKV, BATCH), 256, 0, stream>>>(cache_k, xqk, sp, attn_part);
    // 4) combine chunks
    attn_combine<<<dim3(NH, BATCH), 128, 0, stream>>>(attn_part, attn_out);
    // 5) attn_out @ wo partials
    gemv_part<<<dim3(DMODEL / 256, 16), 256, 0, stream>>>(attn_out, wo, 4096, nullptr, 0, part_out);
    // 6) final reduce -> d_out
    reduce_out<<<256, 256, 0, stream>>>(part_out, out);
}